// Round 1
// baseline (1085.807 us; speedup 1.0000x reference)
//
#include <hip/hip_runtime.h>
#include <hip/hip_bf16.h>
#include <stdint.h>
#include <stddef.h>

// Problem constants
#define B_   16384
#define M_   3
#define D_   2048
#define DH_  1024
#define DV_  512
#define ROWS (B_ * M_)      // 49152
#define NOUT (2 * DH_)      // 2048: cols [0,1024)=q, [1024,2048)=k

typedef _Float16 f16;
typedef f16   f16x8 __attribute__((ext_vector_type(8)));
typedef float f32x4 __attribute__((ext_vector_type(4)));

__device__ __forceinline__ void async16(const void* g, void* l) {
  __builtin_amdgcn_global_load_lds(
      (const __attribute__((address_space(1))) void*)g,
      (__attribute__((address_space(3))) void*)l, 16, 0, 0);
}

// ---- kernel 1: wvf[d] = sum_v Wfc[v] * Wv[v][d]  (grid 8, block 256) ----
__global__ void k_wvf(const float* __restrict__ Wv, const float* __restrict__ Wfc,
                      float* __restrict__ wvf) {
  int d = blockIdx.x * 256 + threadIdx.x;
  float acc = 0.f;
  for (int v = 0; v < DV_; ++v) acc += Wfc[v] * Wv[(size_t)v * D_ + d];
  wvf[d] = acc;
}

// ---- kernel 2: Wh[j][d] fp16; j<1024 -> Wq[j], else Wk[j-1024] ----------
__global__ void k_castw(const float* __restrict__ Wq, const float* __restrict__ Wk,
                        f16* __restrict__ Wh) {
  int t = blockIdx.x * 256 + threadIdx.x;   // 524288 threads, 8 elems each
  int idx = t * 8;
  int j = idx >> 11;
  int d = idx & (D_ - 1);
  const float* src = (j < DH_) ? (Wq + (size_t)j * D_ + d)
                               : (Wk + (size_t)(j - DH_) * D_ + d);
  f32x4 a = *(const f32x4*)src;
  f32x4 b = *(const f32x4*)(src + 4);
  f16x8 h;
  h[0] = (f16)a[0]; h[1] = (f16)a[1]; h[2] = (f16)a[2]; h[3] = (f16)a[3];
  h[4] = (f16)b[0]; h[5] = (f16)b[1]; h[6] = (f16)b[2]; h[7] = (f16)b[3];
  *(f16x8*)(Wh + (size_t)idx) = h;
}

// ---- kernel 3: Xh = fp16(x), vf[row] = x_row . wvf  (grid ROWS, 256) ----
__global__ void k_prep(const float* __restrict__ x, const float* __restrict__ wvf,
                       f16* __restrict__ Xh, float* __restrict__ vf) {
  int row = blockIdx.x;
  int tid = threadIdx.x;
  const float* xr = x + (size_t)row * D_ + tid * 8;
  f32x4 a = *(const f32x4*)xr;
  f32x4 b = *(const f32x4*)(xr + 4);
  const float* wp = wvf + tid * 8;
  f32x4 wa = *(const f32x4*)wp;
  f32x4 wb = *(const f32x4*)(wp + 4);
  f16x8 h;
  h[0] = (f16)a[0]; h[1] = (f16)a[1]; h[2] = (f16)a[2]; h[3] = (f16)a[3];
  h[4] = (f16)b[0]; h[5] = (f16)b[1]; h[6] = (f16)b[2]; h[7] = (f16)b[3];
  *(f16x8*)(Xh + (size_t)row * D_ + tid * 8) = h;
  float acc = a[0]*wa[0] + a[1]*wa[1] + a[2]*wa[2] + a[3]*wa[3]
            + b[0]*wb[0] + b[1]*wb[1] + b[2]*wb[2] + b[3]*wb[3];
  #pragma unroll
  for (int off = 1; off < 64; off <<= 1) acc += __shfl_xor(acc, off);
  __shared__ float red[4];
  if ((tid & 63) == 0) red[tid >> 6] = acc;
  __syncthreads();
  if (tid == 0) vf[row] = red[0] + red[1] + red[2] + red[3];
}

// ---- kernel 4: QK[49152][2048] = Xh @ Wh^T, fp16 in, fp32 acc, fp16 out -
// 128x128 tile, BK=32, 256 threads (4 waves, each a 64x64 quadrant of 4x4
// 16x16x32 MFMAs). global_load_lds width-16 staging, 2-barrier K-loop.
__global__ __launch_bounds__(256, 3) void k_gemm(const f16* __restrict__ Xh,
                                                 const f16* __restrict__ Wh,
                                                 f16* __restrict__ QK) {
  const int ct = blockIdx.x;   // 0..15  column tile
  const int rt = blockIdx.y;   // 0..383 row tile
  const int tid = threadIdx.x;
  const int w = tid >> 6, lane = tid & 63;
  const int wr = w >> 1, wc = w & 1;

  __shared__ __align__(16) f16 lds_a[128 * 32];
  __shared__ __align__(16) f16 lds_b[128 * 32];

  f32x4 acc[4][4] = {};

  // staging: each wave issues 2 A-chunks + 2 B-chunks of 16 rows each.
  // lane l covers row srow=l>>2, 16B chunk (l&3) within the 64B (32-half) row.
  const int srow = lane >> 2;
  const int scol = (lane & 3) * 8;
  const int q0 = w * 2, q1 = q0 + 1;

  const f16* gA0 = Xh + (size_t)(rt * 128 + q0 * 16 + srow) * D_ + scol;
  const f16* gA1 = Xh + (size_t)(rt * 128 + q1 * 16 + srow) * D_ + scol;
  const f16* gB0 = Wh + (size_t)(ct * 128 + q0 * 16 + srow) * D_ + scol;
  const f16* gB1 = Wh + (size_t)(ct * 128 + q1 * 16 + srow) * D_ + scol;

  f16* la0 = &lds_a[q0 * 512];
  f16* la1 = &lds_a[q1 * 512];
  f16* lb0 = &lds_b[q0 * 512];
  f16* lb1 = &lds_b[q1 * 512];

  // fragment read bases: A[m=lane&15][k=(lane>>4)*8+j], same for B (n=lane&15)
  const f16* fa = &lds_a[(size_t)(wr * 64 + (lane & 15)) * 32 + (lane >> 4) * 8];
  const f16* fb = &lds_b[(size_t)(wc * 64 + (lane & 15)) * 32 + (lane >> 4) * 8];

  for (int k0 = 0; k0 < D_; k0 += 32) {
    async16(gA0 + k0, la0);
    async16(gA1 + k0, la1);
    async16(gB0 + k0, lb0);
    async16(gB1 + k0, lb1);
    __syncthreads();   // vmcnt(0) drain + barrier: LDS tile ready
    f16x8 af[4], bf[4];
    #pragma unroll
    for (int i = 0; i < 4; ++i) af[i] = *(const f16x8*)(fa + i * 16 * 32);
    #pragma unroll
    for (int j = 0; j < 4; ++j) bf[j] = *(const f16x8*)(fb + j * 16 * 32);
    #pragma unroll
    for (int i = 0; i < 4; ++i)
      #pragma unroll
      for (int j = 0; j < 4; ++j)
        acc[i][j] = __builtin_amdgcn_mfma_f32_16x16x32_f16(af[i], bf[j], acc[i][j], 0, 0, 0);
    __syncthreads();   // all waves done reading before next stage overwrites
  }

  // epilogue: C/D layout col=lane&15, row=(lane>>4)*4+r
  const int r0 = rt * 128 + wr * 64 + (lane >> 4) * 4;
  const int c0 = ct * 128 + wc * 64 + (lane & 15);
  #pragma unroll
  for (int i = 0; i < 4; ++i)
    #pragma unroll
    for (int j = 0; j < 4; ++j)
      #pragma unroll
      for (int r = 0; r < 4; ++r)
        QK[(size_t)(r0 + i * 16 + r) * NOUT + (c0 + j * 16)] = (f16)acc[i][j][r];
}

// ---- kernel 5: per-batch 3x3 Gram + softmax + weighted vf  (wave/batch) -
__global__ void k_attn(const f16* __restrict__ QK, const float* __restrict__ vf,
                       float* __restrict__ out) {
  int w = threadIdx.x >> 6, lane = threadIdx.x & 63;
  int b = blockIdx.x * 4 + w;
  const f16* base = QK + (size_t)b * M_ * NOUT;
  f16x8 q[3][2], k[3][2];
  #pragma unroll
  for (int i = 0; i < 3; ++i) {
    q[i][0] = *(const f16x8*)(base + i * NOUT + lane * 8);
    q[i][1] = *(const f16x8*)(base + i * NOUT + 512 + lane * 8);
    k[i][0] = *(const f16x8*)(base + i * NOUT + 1024 + lane * 8);
    k[i][1] = *(const f16x8*)(base + i * NOUT + 1536 + lane * 8);
  }
  float s[3][3];
  #pragma unroll
  for (int i = 0; i < 3; ++i)
    #pragma unroll
    for (int j = 0; j < 3; ++j) {
      float a = 0.f;
      #pragma unroll
      for (int c = 0; c < 2; ++c)
        #pragma unroll
        for (int t = 0; t < 8; ++t)
          a += (float)q[i][c][t] * (float)k[j][c][t];
      s[i][j] = a;
    }
  #pragma unroll
  for (int i = 0; i < 3; ++i)
    #pragma unroll
    for (int j = 0; j < 3; ++j)
      #pragma unroll
      for (int off = 1; off < 64; off <<= 1)
        s[i][j] += __shfl_xor(s[i][j], off);
  if (lane == 0) {
    float attn[3] = {0.f, 0.f, 0.f};
    #pragma unroll
    for (int i = 0; i < 3; ++i) {
      float m = fmaxf(s[i][0], fmaxf(s[i][1], s[i][2]));
      float e0 = expf(s[i][0] - m), e1 = expf(s[i][1] - m), e2 = expf(s[i][2] - m);
      float inv = 1.f / (e0 + e1 + e2);
      attn[0] += e0 * inv; attn[1] += e1 * inv; attn[2] += e2 * inv;
    }
    float o = attn[0] * vf[b * 3 + 0] + attn[1] * vf[b * 3 + 1] + attn[2] * vf[b * 3 + 2];
    out[b] = o * (1.f / 3.f);
  }
}

extern "C" void kernel_launch(void* const* d_in, const int* in_sizes, int n_in,
                              void* d_out, int out_size, void* d_ws, size_t ws_size,
                              hipStream_t stream) {
  const float* x   = (const float*)d_in[0];
  const float* Wq  = (const float*)d_in[1];
  const float* Wk  = (const float*)d_in[2];
  const float* Wv  = (const float*)d_in[3];
  const float* Wfc = (const float*)d_in[4];
  float* out = (float*)d_out;

  char* ws = (char*)d_ws;
  f16*   Xh  = (f16*)(ws);                          // 49152*2048*2 = 201326592
  f16*   QK  = (f16*)(ws + 201326592ull);           // 201326592
  f16*   Wh  = (f16*)(ws + 402653184ull);           // 2048*2048*2 = 8388608
  float* wvf = (float*)(ws + 411041792ull);         // 8192
  float* vf  = (float*)(ws + 411049984ull);         // 196608

  k_wvf  <<<8,              256, 0, stream>>>(Wv, Wfc, wvf);
  k_castw<<<2048,           256, 0, stream>>>(Wq, Wk, Wh);
  k_prep <<<ROWS,           256, 0, stream>>>(x, wvf, Xh, vf);
  k_gemm <<<dim3(16, 384),  256, 0, stream>>>(Xh, Wh, QK);
  k_attn <<<B_ / 4,         256, 0, stream>>>(QK, vf, out);
}

// Round 2
// 1065.930 us; speedup vs baseline: 1.0186x; 1.0186x over previous
//
#include <hip/hip_runtime.h>
#include <hip/hip_bf16.h>
#include <stdint.h>
#include <stddef.h>

// Problem constants
#define B_   16384
#define M_   3
#define D_   2048
#define DH_  1024
#define DV_  512
#define ROWS (B_ * M_)      // 49152
#define NOUT (2 * DH_)      // 2048: cols [0,1024)=q, [1024,2048)=k

typedef _Float16 f16;
typedef f16   f16x8 __attribute__((ext_vector_type(8)));
typedef float f32x4 __attribute__((ext_vector_type(4)));

__device__ __forceinline__ void async16(const void* g, void* l) {
  __builtin_amdgcn_global_load_lds(
      (const __attribute__((address_space(1))) void*)g,
      (__attribute__((address_space(3))) void*)l, 16, 0, 0);
}

// ---- kernel 1: wvf[d] = sum_v Wfc[v] * Wv[v][d]  (grid 64, block 256) ---
// block covers 32 d-cols; 8 v-slices of 64 rows each, LDS-reduced.
__global__ void k_wvf(const float* __restrict__ Wv, const float* __restrict__ Wfc,
                      float* __restrict__ wvf) {
  int dl = threadIdx.x & 31;
  int vs = threadIdx.x >> 5;
  int d = blockIdx.x * 32 + dl;
  float acc = 0.f;
  #pragma unroll 8
  for (int v = vs * 64; v < vs * 64 + 64; ++v)
    acc += Wfc[v] * Wv[(size_t)v * D_ + d];
  __shared__ float red[8][32];
  red[vs][dl] = acc;
  __syncthreads();
  if (threadIdx.x < 32) {
    float s = 0.f;
    #pragma unroll
    for (int i = 0; i < 8; ++i) s += red[i][threadIdx.x];
    wvf[blockIdx.x * 32 + threadIdx.x] = s;
  }
}

// ---- kernel 2: Wh[j][d] fp16; j<1024 -> Wq[j], else Wk[j-1024] ----------
__global__ void k_castw(const float* __restrict__ Wq, const float* __restrict__ Wk,
                        f16* __restrict__ Wh) {
  int t = blockIdx.x * 256 + threadIdx.x;   // 524288 threads, 8 elems each
  int idx = t * 8;
  int j = idx >> 11;
  int d = idx & (D_ - 1);
  const float* src = (j < DH_) ? (Wq + (size_t)j * D_ + d)
                               : (Wk + (size_t)(j - DH_) * D_ + d);
  f32x4 a = *(const f32x4*)src;
  f32x4 b = *(const f32x4*)(src + 4);
  f16x8 h;
  h[0] = (f16)a[0]; h[1] = (f16)a[1]; h[2] = (f16)a[2]; h[3] = (f16)a[3];
  h[4] = (f16)b[0]; h[5] = (f16)b[1]; h[6] = (f16)b[2]; h[7] = (f16)b[3];
  *(f16x8*)(Wh + (size_t)idx) = h;
}

// ---- kernel 3: Xh = fp16(x), vf[row] = x_row . wvf ----------------------
// wave-per-row, pure shuffle reduction, no __syncthreads. grid ROWS/4.
__global__ void k_prep(const float* __restrict__ x, const float* __restrict__ wvf,
                       f16* __restrict__ Xh, float* __restrict__ vf) {
  int w = threadIdx.x >> 6, lane = threadIdx.x & 63;
  int row = blockIdx.x * 4 + w;
  const float* xr = x + (size_t)row * D_;
  f16* xo = Xh + (size_t)row * D_;
  float acc = 0.f;
  #pragma unroll
  for (int p = 0; p < 4; ++p) {
    int col = p * 512 + lane * 8;
    f32x4 a = *(const f32x4*)(xr + col);
    f32x4 b = *(const f32x4*)(xr + col + 4);
    f32x4 wa = *(const f32x4*)(wvf + col);
    f32x4 wb = *(const f32x4*)(wvf + col + 4);
    f16x8 h;
    h[0] = (f16)a[0]; h[1] = (f16)a[1]; h[2] = (f16)a[2]; h[3] = (f16)a[3];
    h[4] = (f16)b[0]; h[5] = (f16)b[1]; h[6] = (f16)b[2]; h[7] = (f16)b[3];
    *(f16x8*)(xo + col) = h;
    acc += a[0]*wa[0] + a[1]*wa[1] + a[2]*wa[2] + a[3]*wa[3]
         + b[0]*wb[0] + b[1]*wb[1] + b[2]*wb[2] + b[3]*wb[3];
  }
  #pragma unroll
  for (int off = 1; off < 64; off <<= 1) acc += __shfl_xor(acc, off);
  if (lane == 0) vf[row] = acc;
}

// ---- kernel 4: QK[49152][2048] = Xh @ Wh^T, fp16 in, fp32 acc, fp16 out -
// 128x128 tile, BK=32, 4 waves each a 64x64 quadrant of 4x4 16x16x32 MFMAs.
// LDS chunk XOR-swizzle: chunk c of row r stored at r*64B + (c^((r>>1)&3))*16B
// -> ds_read_b128 fragment reads are 2-way (free) instead of 8-way.
__global__ __launch_bounds__(256, 4) void k_gemm(const f16* __restrict__ Xh,
                                                 const f16* __restrict__ Wh,
                                                 f16* __restrict__ QK) {
  const int ct = blockIdx.x;   // 0..15  column tile
  const int rt = blockIdx.y;   // 0..383 row tile
  const int tid = threadIdx.x;
  const int w = tid >> 6, lane = tid & 63;
  const int wr = w >> 1, wc = w & 1;

  __shared__ __align__(16) f16 lds_a[128 * 32];
  __shared__ __align__(16) f16 lds_b[128 * 32];

  f32x4 acc[4][4] = {};

  // staging: lane l's LDS dest is fixed at base + l*16B = (row l>>2, slot l&3).
  // To realize the swizzled layout, permute the global SOURCE chunk:
  const int srow = lane >> 2;                          // row within 16-row chunk
  const int schunk = (lane & 3) ^ ((lane >> 3) & 3);   // global chunk index
  const int scol = schunk * 8;
  const int q0 = w * 2, q1 = q0 + 1;

  const f16* gA0 = Xh + (size_t)(rt * 128 + q0 * 16 + srow) * D_ + scol;
  const f16* gA1 = Xh + (size_t)(rt * 128 + q1 * 16 + srow) * D_ + scol;
  const f16* gB0 = Wh + (size_t)(ct * 128 + q0 * 16 + srow) * D_ + scol;
  const f16* gB1 = Wh + (size_t)(ct * 128 + q1 * 16 + srow) * D_ + scol;

  f16* la0 = &lds_a[q0 * 512];
  f16* la1 = &lds_a[q1 * 512];
  f16* lb0 = &lds_b[q0 * 512];
  f16* lb1 = &lds_b[q1 * 512];

  // fragment read: row r=lane&15, k-chunk q=lane>>4, swizzled slot q^((r>>1)&3)
  const int fr = lane & 15;
  const int fq = (lane >> 4) ^ ((fr >> 1) & 3);
  const f16* fa = &lds_a[(size_t)(wr * 64 + fr) * 32 + fq * 8];
  const f16* fb = &lds_b[(size_t)(wc * 64 + fr) * 32 + fq * 8];

  for (int k0 = 0; k0 < D_; k0 += 32) {
    async16(gA0 + k0, la0);
    async16(gA1 + k0, la1);
    async16(gB0 + k0, lb0);
    async16(gB1 + k0, lb1);
    __syncthreads();   // vmcnt(0) drain + barrier: LDS tile ready
    f16x8 af[4], bf[4];
    #pragma unroll
    for (int i = 0; i < 4; ++i) af[i] = *(const f16x8*)(fa + i * 16 * 32);
    #pragma unroll
    for (int j = 0; j < 4; ++j) bf[j] = *(const f16x8*)(fb + j * 16 * 32);
    #pragma unroll
    for (int i = 0; i < 4; ++i)
      #pragma unroll
      for (int j = 0; j < 4; ++j)
        acc[i][j] = __builtin_amdgcn_mfma_f32_16x16x32_f16(af[i], bf[j], acc[i][j], 0, 0, 0);
    __syncthreads();   // all waves done reading before next stage overwrites
  }

  // epilogue: C/D layout col=lane&15, row=(lane>>4)*4+r
  const int r0 = rt * 128 + wr * 64 + (lane >> 4) * 4;
  const int c0 = ct * 128 + wc * 64 + (lane & 15);
  #pragma unroll
  for (int i = 0; i < 4; ++i)
    #pragma unroll
    for (int j = 0; j < 4; ++j)
      #pragma unroll
      for (int r = 0; r < 4; ++r)
        QK[(size_t)(r0 + i * 16 + r) * NOUT + (c0 + j * 16)] = (f16)acc[i][j][r];
}

// ---- kernel 5: per-batch 3x3 Gram + softmax + weighted vf  (wave/batch) -
__global__ void k_attn(const f16* __restrict__ QK, const float* __restrict__ vf,
                       float* __restrict__ out) {
  int w = threadIdx.x >> 6, lane = threadIdx.x & 63;
  int b = blockIdx.x * 4 + w;
  const f16* base = QK + (size_t)b * M_ * NOUT;
  f16x8 q[3][2], k[3][2];
  #pragma unroll
  for (int i = 0; i < 3; ++i) {
    q[i][0] = *(const f16x8*)(base + i * NOUT + lane * 8);
    q[i][1] = *(const f16x8*)(base + i * NOUT + 512 + lane * 8);
    k[i][0] = *(const f16x8*)(base + i * NOUT + 1024 + lane * 8);
    k[i][1] = *(const f16x8*)(base + i * NOUT + 1536 + lane * 8);
  }
  float s[3][3];
  #pragma unroll
  for (int i = 0; i < 3; ++i)
    #pragma unroll
    for (int j = 0; j < 3; ++j) {
      float a = 0.f;
      #pragma unroll
      for (int c = 0; c < 2; ++c)
        #pragma unroll
        for (int t = 0; t < 8; ++t)
          a += (float)q[i][c][t] * (float)k[j][c][t];
      s[i][j] = a;
    }
  #pragma unroll
  for (int i = 0; i < 3; ++i)
    #pragma unroll
    for (int j = 0; j < 3; ++j)
      #pragma unroll
      for (int off = 1; off < 64; off <<= 1)
        s[i][j] += __shfl_xor(s[i][j], off);
  if (lane == 0) {
    float attn[3] = {0.f, 0.f, 0.f};
    #pragma unroll
    for (int i = 0; i < 3; ++i) {
      float m = fmaxf(s[i][0], fmaxf(s[i][1], s[i][2]));
      float e0 = expf(s[i][0] - m), e1 = expf(s[i][1] - m), e2 = expf(s[i][2] - m);
      float inv = 1.f / (e0 + e1 + e2);
      attn[0] += e0 * inv; attn[1] += e1 * inv; attn[2] += e2 * inv;
    }
    float o = attn[0] * vf[b * 3 + 0] + attn[1] * vf[b * 3 + 1] + attn[2] * vf[b * 3 + 2];
    out[b] = o * (1.f / 3.f);
  }
}

extern "C" void kernel_launch(void* const* d_in, const int* in_sizes, int n_in,
                              void* d_out, int out_size, void* d_ws, size_t ws_size,
                              hipStream_t stream) {
  const float* x   = (const float*)d_in[0];
  const float* Wq  = (const float*)d_in[1];
  const float* Wk  = (const float*)d_in[2];
  const float* Wv  = (const float*)d_in[3];
  const float* Wfc = (const float*)d_in[4];
  float* out = (float*)d_out;

  char* ws = (char*)d_ws;
  f16*   Xh  = (f16*)(ws);                          // 49152*2048*2 = 201326592
  f16*   QK  = (f16*)(ws + 201326592ull);           // 201326592
  f16*   Wh  = (f16*)(ws + 402653184ull);           // 2048*2048*2 = 8388608
  float* wvf = (float*)(ws + 411041792ull);         // 8192
  float* vf  = (float*)(ws + 411049984ull);         // 196608

  k_wvf  <<<64,             256, 0, stream>>>(Wv, Wfc, wvf);
  k_castw<<<2048,           256, 0, stream>>>(Wq, Wk, Wh);
  k_prep <<<ROWS / 4,       256, 0, stream>>>(x, wvf, Xh, vf);
  k_gemm <<<dim3(16, 384),  256, 0, stream>>>(Xh, Wh, QK);
  k_attn <<<B_ / 4,         256, 0, stream>>>(QK, vf, out);
}

// Round 3
// 1010.543 us; speedup vs baseline: 1.0745x; 1.0548x over previous
//
#include <hip/hip_runtime.h>
#include <hip/hip_bf16.h>
#include <stdint.h>
#include <stddef.h>

// Problem constants
#define B_   16384
#define M_   3
#define D_   2048
#define DH_  1024
#define DV_  512
#define ROWS (B_ * M_)      // 49152
#define NOUT (2 * DH_)      // 2048: cols [0,1024)=q, [1024,2048)=k

typedef _Float16 f16;
typedef f16   f16x8 __attribute__((ext_vector_type(8)));
typedef float f32x4 __attribute__((ext_vector_type(4)));

__device__ __forceinline__ void async16(const void* g, void* l) {
  __builtin_amdgcn_global_load_lds(
      (const __attribute__((address_space(1))) void*)g,
      (__attribute__((address_space(3))) void*)l, 16, 0, 0);
}

// ---- kernel 1: wvf[d] = sum_v Wfc[v] * Wv[v][d]  (grid 64, block 256) ---
__global__ void k_wvf(const float* __restrict__ Wv, const float* __restrict__ Wfc,
                      float* __restrict__ wvf) {
  int dl = threadIdx.x & 31;
  int vs = threadIdx.x >> 5;
  int d = blockIdx.x * 32 + dl;
  float acc = 0.f;
  #pragma unroll 8
  for (int v = vs * 64; v < vs * 64 + 64; ++v)
    acc += Wfc[v] * Wv[(size_t)v * D_ + d];
  __shared__ float red[8][32];
  red[vs][dl] = acc;
  __syncthreads();
  if (threadIdx.x < 32) {
    float s = 0.f;
    #pragma unroll
    for (int i = 0; i < 8; ++i) s += red[i][threadIdx.x];
    wvf[blockIdx.x * 32 + threadIdx.x] = s;
  }
}

// ---- kernel 2: Wh[j][d] fp16; j<1024 -> Wq[j], else Wk[j-1024] ----------
__global__ void k_castw(const float* __restrict__ Wq, const float* __restrict__ Wk,
                        f16* __restrict__ Wh) {
  int t = blockIdx.x * 256 + threadIdx.x;   // 524288 threads, 8 elems each
  int idx = t * 8;
  int j = idx >> 11;
  int d = idx & (D_ - 1);
  const float* src = (j < DH_) ? (Wq + (size_t)j * D_ + d)
                               : (Wk + (size_t)(j - DH_) * D_ + d);
  f32x4 a = *(const f32x4*)src;
  f32x4 b = *(const f32x4*)(src + 4);
  f16x8 h;
  h[0] = (f16)a[0]; h[1] = (f16)a[1]; h[2] = (f16)a[2]; h[3] = (f16)a[3];
  h[4] = (f16)b[0]; h[5] = (f16)b[1]; h[6] = (f16)b[2]; h[7] = (f16)b[3];
  *(f16x8*)(Wh + (size_t)idx) = h;
}

// ---- kernel 3: Xh = fp16(x), vf[row] = x_row . wvf ----------------------
// wave-per-row, pure shuffle reduction, no __syncthreads. grid ROWS/4.
__global__ void k_prep(const float* __restrict__ x, const float* __restrict__ wvf,
                       f16* __restrict__ Xh, float* __restrict__ vf) {
  int w = threadIdx.x >> 6, lane = threadIdx.x & 63;
  int row = blockIdx.x * 4 + w;
  const float* xr = x + (size_t)row * D_;
  f16* xo = Xh + (size_t)row * D_;
  float acc = 0.f;
  #pragma unroll
  for (int p = 0; p < 4; ++p) {
    int col = p * 512 + lane * 8;
    f32x4 a = *(const f32x4*)(xr + col);
    f32x4 b = *(const f32x4*)(xr + col + 4);
    f32x4 wa = *(const f32x4*)(wvf + col);
    f32x4 wb = *(const f32x4*)(wvf + col + 4);
    f16x8 h;
    h[0] = (f16)a[0]; h[1] = (f16)a[1]; h[2] = (f16)a[2]; h[3] = (f16)a[3];
    h[4] = (f16)b[0]; h[5] = (f16)b[1]; h[6] = (f16)b[2]; h[7] = (f16)b[3];
    *(f16x8*)(xo + col) = h;
    acc += a[0]*wa[0] + a[1]*wa[1] + a[2]*wa[2] + a[3]*wa[3]
         + b[0]*wb[0] + b[1]*wb[1] + b[2]*wb[2] + b[3]*wb[3];
  }
  #pragma unroll
  for (int off = 1; off < 64; off <<= 1) acc += __shfl_xor(acc, off);
  if (lane == 0) vf[row] = acc;
}

// ---- kernel 4: QK = Xh @ Wh^T, 128x128 tile, BK=64 ----------------------
// 32 K-iterations (vs 64 at BK=32): halves the vmcnt(0)+barrier drains,
// doubles MFMA per drain. LDS 32 KB (2x 128x64 f16) -> 5 blocks/CU cap.
// Swizzle: 128-B rows == bank period, so unswizzled frag reads would be
// 16-way conflicted; store chunk c of row r at slot c^(r&7) -> 2-way (free).
__global__ __launch_bounds__(256, 3) void k_gemm(const f16* __restrict__ Xh,
                                                 const f16* __restrict__ Wh,
                                                 f16* __restrict__ QK) {
  const int ct = blockIdx.x;   // 0..15  column tile
  const int rt = blockIdx.y;   // 0..383 row tile
  const int tid = threadIdx.x;
  const int w = tid >> 6, lane = tid & 63;
  const int wr = w >> 1, wc = w & 1;

  __shared__ __align__(16) f16 lds_a[128 * 64];
  __shared__ __align__(16) f16 lds_b[128 * 64];

  f32x4 acc[4][4] = {};

  // staging: 4 issues/wave for A + 4 for B; each issue = 8 rows x 128 B.
  // lane l -> row (l>>3) within issue, LDS slot l&7; global source chunk
  // is pre-permuted so LDS slot holds chunk (l&7)^(row&7).
  const int srow = lane >> 3;
  const int schunk = (lane & 7) ^ srow;
  const int scol = schunk * 8;

  const f16* gA[4]; const f16* gB[4];
  f16 *la[4], *lb[4];
  #pragma unroll
  for (int t = 0; t < 4; ++t) {
    int rowA = w * 32 + t * 8;   // base row of this issue within the 128-tile
    gA[t] = Xh + (size_t)(rt * 128 + rowA + srow) * D_ + scol;
    gB[t] = Wh + (size_t)(ct * 128 + rowA + srow) * D_ + scol;
    la[t] = &lds_a[rowA * 64];
    lb[t] = &lds_b[rowA * 64];
  }

  // fragment read bases: row m=lane&15, k-quad kq=lane>>4;
  // k-step s uses slot (s*4+kq)^(m&7)
  const int m = lane & 15;
  const int kq = lane >> 4;
  const f16* fa0 = &lds_a[(size_t)(wr * 64 + m) * 64 + ((kq    ) ^ (m & 7)) * 8];
  const f16* fa1 = &lds_a[(size_t)(wr * 64 + m) * 64 + ((kq + 4) ^ (m & 7)) * 8];
  const f16* fb0 = &lds_b[(size_t)(wc * 64 + m) * 64 + ((kq    ) ^ (m & 7)) * 8];
  const f16* fb1 = &lds_b[(size_t)(wc * 64 + m) * 64 + ((kq + 4) ^ (m & 7)) * 8];

  for (int k0 = 0; k0 < D_; k0 += 64) {
    #pragma unroll
    for (int t = 0; t < 4; ++t) async16(gA[t] + k0, la[t]);
    #pragma unroll
    for (int t = 0; t < 4; ++t) async16(gB[t] + k0, lb[t]);
    __syncthreads();   // vmcnt(0) drain + barrier: LDS tile ready
    {
      f16x8 af[4], bf[4];
      #pragma unroll
      for (int i = 0; i < 4; ++i) af[i] = *(const f16x8*)(fa0 + i * 16 * 64);
      #pragma unroll
      for (int j = 0; j < 4; ++j) bf[j] = *(const f16x8*)(fb0 + j * 16 * 64);
      #pragma unroll
      for (int i = 0; i < 4; ++i)
        #pragma unroll
        for (int j = 0; j < 4; ++j)
          acc[i][j] = __builtin_amdgcn_mfma_f32_16x16x32_f16(af[i], bf[j], acc[i][j], 0, 0, 0);
    }
    {
      f16x8 af[4], bf[4];
      #pragma unroll
      for (int i = 0; i < 4; ++i) af[i] = *(const f16x8*)(fa1 + i * 16 * 64);
      #pragma unroll
      for (int j = 0; j < 4; ++j) bf[j] = *(const f16x8*)(fb1 + j * 16 * 64);
      #pragma unroll
      for (int i = 0; i < 4; ++i)
        #pragma unroll
        for (int j = 0; j < 4; ++j)
          acc[i][j] = __builtin_amdgcn_mfma_f32_16x16x32_f16(af[i], bf[j], acc[i][j], 0, 0, 0);
    }
    __syncthreads();   // all waves done reading before next stage overwrites
  }

  // epilogue: C/D layout col=lane&15, row=(lane>>4)*4+r
  const int r0 = rt * 128 + wr * 64 + (lane >> 4) * 4;
  const int c0 = ct * 128 + wc * 64 + (lane & 15);
  #pragma unroll
  for (int i = 0; i < 4; ++i)
    #pragma unroll
    for (int j = 0; j < 4; ++j)
      #pragma unroll
      for (int r = 0; r < 4; ++r)
        QK[(size_t)(r0 + i * 16 + r) * NOUT + (c0 + j * 16)] = (f16)acc[i][j][r];
}

// ---- kernel 5: per-batch 3x3 Gram + softmax + weighted vf  (wave/batch) -
__global__ void k_attn(const f16* __restrict__ QK, const float* __restrict__ vf,
                       float* __restrict__ out) {
  int w = threadIdx.x >> 6, lane = threadIdx.x & 63;
  int b = blockIdx.x * 4 + w;
  const f16* base = QK + (size_t)b * M_ * NOUT;
  f16x8 q[3][2], k[3][2];
  #pragma unroll
  for (int i = 0; i < 3; ++i) {
    q[i][0] = *(const f16x8*)(base + i * NOUT + lane * 8);
    q[i][1] = *(const f16x8*)(base + i * NOUT + 512 + lane * 8);
    k[i][0] = *(const f16x8*)(base + i * NOUT + 1024 + lane * 8);
    k[i][1] = *(const f16x8*)(base + i * NOUT + 1536 + lane * 8);
  }
  float s[3][3];
  #pragma unroll
  for (int i = 0; i < 3; ++i)
    #pragma unroll
    for (int j = 0; j < 3; ++j) {
      float a = 0.f;
      #pragma unroll
      for (int c = 0; c < 2; ++c)
        #pragma unroll
        for (int t = 0; t < 8; ++t)
          a += (float)q[i][c][t] * (float)k[j][c][t];
      s[i][j] = a;
    }
  #pragma unroll
  for (int i = 0; i < 3; ++i)
    #pragma unroll
    for (int j = 0; j < 3; ++j)
      #pragma unroll
      for (int off = 1; off < 64; off <<= 1)
        s[i][j] += __shfl_xor(s[i][j], off);
  if (lane == 0) {
    float attn[3] = {0.f, 0.f, 0.f};
    #pragma unroll
    for (int i = 0; i < 3; ++i) {
      float m = fmaxf(s[i][0], fmaxf(s[i][1], s[i][2]));
      float e0 = expf(s[i][0] - m), e1 = expf(s[i][1] - m), e2 = expf(s[i][2] - m);
      float inv = 1.f / (e0 + e1 + e2);
      attn[0] += e0 * inv; attn[1] += e1 * inv; attn[2] += e2 * inv;
    }
    float o = attn[0] * vf[b * 3 + 0] + attn[1] * vf[b * 3 + 1] + attn[2] * vf[b * 3 + 2];
    out[b] = o * (1.f / 3.f);
  }
}

extern "C" void kernel_launch(void* const* d_in, const int* in_sizes, int n_in,
                              void* d_out, int out_size, void* d_ws, size_t ws_size,
                              hipStream_t stream) {
  const float* x   = (const float*)d_in[0];
  const float* Wq  = (const float*)d_in[1];
  const float* Wk  = (const float*)d_in[2];
  const float* Wv  = (const float*)d_in[3];
  const float* Wfc = (const float*)d_in[4];
  float* out = (float*)d_out;

  char* ws = (char*)d_ws;
  f16*   Xh  = (f16*)(ws);                          // 49152*2048*2 = 201326592
  f16*   QK  = (f16*)(ws + 201326592ull);           // 201326592
  f16*   Wh  = (f16*)(ws + 402653184ull);           // 2048*2048*2 = 8388608
  float* wvf = (float*)(ws + 411041792ull);         // 8192
  float* vf  = (float*)(ws + 411049984ull);         // 196608

  k_wvf  <<<64,             256, 0, stream>>>(Wv, Wfc, wvf);
  k_castw<<<2048,           256, 0, stream>>>(Wq, Wk, Wh);
  k_prep <<<ROWS / 4,       256, 0, stream>>>(x, wvf, Xh, vf);
  k_gemm <<<dim3(16, 384),  256, 0, stream>>>(Xh, Wh, QK);
  k_attn <<<B_ / 4,         256, 0, stream>>>(QK, vf, out);
}

// Round 4
// 976.820 us; speedup vs baseline: 1.1116x; 1.0345x over previous
//
#include <hip/hip_runtime.h>
#include <hip/hip_bf16.h>
#include <stdint.h>
#include <stddef.h>

// Problem constants
#define B_   16384
#define M_   3
#define D_   2048
#define DH_  1024
#define DV_  512
#define ROWS (B_ * M_)      // 49152
#define RT_ROWS 126         // rows per GEMM row-tile (42 whole batches)
#define RT_BATCH 42
#define NRT 391             // ceil(49152/126)
#define NHT 16              // h-tiles of 64

typedef _Float16 f16;
typedef f16   f16x8 __attribute__((ext_vector_type(8)));
typedef float f32x4 __attribute__((ext_vector_type(4)));

__device__ __forceinline__ void async16(const void* g, void* l) {
  __builtin_amdgcn_global_load_lds(
      (const __attribute__((address_space(1))) void*)g,
      (__attribute__((address_space(3))) void*)l, 16, 0, 0);
}

// ---- kernel 1: wvf[d] = sum_v Wfc[v] * Wv[v][d]  (grid 64, block 256) ---
__global__ void k_wvf(const float* __restrict__ Wv, const float* __restrict__ Wfc,
                      float* __restrict__ wvf) {
  int dl = threadIdx.x & 31;
  int vs = threadIdx.x >> 5;
  int d = blockIdx.x * 32 + dl;
  float acc = 0.f;
  #pragma unroll 8
  for (int v = vs * 64; v < vs * 64 + 64; ++v)
    acc += Wfc[v] * Wv[(size_t)v * D_ + d];
  __shared__ float red[8][32];
  red[vs][dl] = acc;
  __syncthreads();
  if (threadIdx.x < 32) {
    float s = 0.f;
    #pragma unroll
    for (int i = 0; i < 8; ++i) s += red[i][threadIdx.x];
    wvf[blockIdx.x * 32 + threadIdx.x] = s;
  }
}

// ---- kernel 2: Wh[j][d] fp16; j<1024 -> Wq[j], else Wk[j-1024] ----------
__global__ void k_castw(const float* __restrict__ Wq, const float* __restrict__ Wk,
                        f16* __restrict__ Wh) {
  int t = blockIdx.x * 256 + threadIdx.x;
  int idx = t * 8;
  int j = idx >> 11;
  int d = idx & (D_ - 1);
  const float* src = (j < DH_) ? (Wq + (size_t)j * D_ + d)
                               : (Wk + (size_t)(j - DH_) * D_ + d);
  f32x4 a = *(const f32x4*)src;
  f32x4 b = *(const f32x4*)(src + 4);
  f16x8 h;
  h[0] = (f16)a[0]; h[1] = (f16)a[1]; h[2] = (f16)a[2]; h[3] = (f16)a[3];
  h[4] = (f16)b[0]; h[5] = (f16)b[1]; h[6] = (f16)b[2]; h[7] = (f16)b[3];
  *(f16x8*)(Wh + (size_t)idx) = h;
}

// ---- kernel 3: Xh = fp16(x), vf[row] = x_row . wvf ----------------------
__global__ void k_prep(const float* __restrict__ x, const float* __restrict__ wvf,
                       f16* __restrict__ Xh, float* __restrict__ vf) {
  int w = threadIdx.x >> 6, lane = threadIdx.x & 63;
  int row = blockIdx.x * 4 + w;
  const float* xr = x + (size_t)row * D_;
  f16* xo = Xh + (size_t)row * D_;
  float acc = 0.f;
  #pragma unroll
  for (int p = 0; p < 4; ++p) {
    int col = p * 512 + lane * 8;
    f32x4 a = *(const f32x4*)(xr + col);
    f32x4 b = *(const f32x4*)(xr + col + 4);
    f32x4 wa = *(const f32x4*)(wvf + col);
    f32x4 wb = *(const f32x4*)(wvf + col + 4);
    f16x8 h;
    h[0] = (f16)a[0]; h[1] = (f16)a[1]; h[2] = (f16)a[2]; h[3] = (f16)a[3];
    h[4] = (f16)b[0]; h[5] = (f16)b[1]; h[6] = (f16)b[2]; h[7] = (f16)b[3];
    *(f16x8*)(xo + col) = h;
    acc += a[0]*wa[0] + a[1]*wa[1] + a[2]*wa[2] + a[3]*wa[3]
         + b[0]*wb[0] + b[1]*wb[1] + b[2]*wb[2] + b[3]*wb[3];
  }
  #pragma unroll
  for (int off = 1; off < 64; off <<= 1) acc += __shfl_xor(acc, off);
  if (lane == 0) vf[row] = acc;
}

// ---- kernel 4: fused GEMM + partial Gram --------------------------------
// Block (ht, rt): 126 rows (42 batches) x paired 64 q-cols + 64 k-cols at
// h in [ht*64, ht*64+64). BK=64, swizzled LDS (slot = chunk ^ (row&7)).
// Epilogue: q/k halves -> LDS (reusing staging buffers, exactly 16 KB each),
// 42x9 partial Gram dots over 64 h, write S_part[b][ht][9]. No QK in HBM.
__global__ __launch_bounds__(256, 3) void k_gemm(const f16* __restrict__ Xh,
                                                 const f16* __restrict__ Wh,
                                                 float* __restrict__ S_part) {
  const int ht = blockIdx.x;   // 0..15  h-tile
  const int rt = blockIdx.y;   // 0..390 row tile (126 rows each)
  const int tid = threadIdx.x;
  const int w = tid >> 6, lane = tid & 63;
  const int wr = w >> 1, wc = w & 1;

  __shared__ __align__(16) f16 lds_a[128 * 64];   // A staging / q epilogue
  __shared__ __align__(16) f16 lds_b[128 * 64];   // B staging / k epilogue

  f32x4 acc[4][4] = {};

  // staging: 4 issues/wave for A + 4 for B; each issue = 8 rows x 128 B.
  // lane l -> row (l>>3) within issue, LDS slot l&7; source chunk (l&7)^row.
  const int srow = lane >> 3;
  const int schunk = (lane & 7) ^ srow;
  const int scol = schunk * 8;

  const f16* gA[4]; const f16* gB[4];
  f16 *la[4], *lb[4];
  #pragma unroll
  for (int t = 0; t < 4; ++t) {
    int rowT = w * 32 + t * 8;                 // tile-local row 0..127
    int ra = rt * RT_ROWS + rowT + srow;       // global X row (2-row overlap)
    if (ra > ROWS - 1) ra = ROWS - 1;
    gA[t] = Xh + (size_t)ra * D_ + scol;
    int c = rowT + srow;                       // tile col index for B
    int rb = (c < 64) ? (ht * 64 + c) : (DH_ + ht * 64 + (c - 64));
    gB[t] = Wh + (size_t)rb * D_ + scol;
    la[t] = &lds_a[rowT * 64];
    lb[t] = &lds_b[rowT * 64];
  }

  // fragment reads: row m=lane&15, k-quad kq=lane>>4; slot (s*4+kq)^(m&7)
  const int m = lane & 15;
  const int kq = lane >> 4;
  const f16* fa0 = &lds_a[(size_t)(wr * 64 + m) * 64 + ((kq    ) ^ (m & 7)) * 8];
  const f16* fa1 = &lds_a[(size_t)(wr * 64 + m) * 64 + ((kq + 4) ^ (m & 7)) * 8];
  const f16* fb0 = &lds_b[(size_t)(wc * 64 + m) * 64 + ((kq    ) ^ (m & 7)) * 8];
  const f16* fb1 = &lds_b[(size_t)(wc * 64 + m) * 64 + ((kq + 4) ^ (m & 7)) * 8];

  for (int k0 = 0; k0 < D_; k0 += 64) {
    #pragma unroll
    for (int t = 0; t < 4; ++t) async16(gA[t] + k0, la[t]);
    #pragma unroll
    for (int t = 0; t < 4; ++t) async16(gB[t] + k0, lb[t]);
    __syncthreads();
    {
      f16x8 af[4], bf[4];
      #pragma unroll
      for (int i = 0; i < 4; ++i) af[i] = *(const f16x8*)(fa0 + i * 16 * 64);
      #pragma unroll
      for (int j = 0; j < 4; ++j) bf[j] = *(const f16x8*)(fb0 + j * 16 * 64);
      #pragma unroll
      for (int i = 0; i < 4; ++i)
        #pragma unroll
        for (int j = 0; j < 4; ++j)
          acc[i][j] = __builtin_amdgcn_mfma_f32_16x16x32_f16(af[i], bf[j], acc[i][j], 0, 0, 0);
    }
    {
      f16x8 af[4], bf[4];
      #pragma unroll
      for (int i = 0; i < 4; ++i) af[i] = *(const f16x8*)(fa1 + i * 16 * 64);
      #pragma unroll
      for (int j = 0; j < 4; ++j) bf[j] = *(const f16x8*)(fb1 + j * 16 * 64);
      #pragma unroll
      for (int i = 0; i < 4; ++i)
        #pragma unroll
        for (int j = 0; j < 4; ++j)
          acc[i][j] = __builtin_amdgcn_mfma_f32_16x16x32_f16(af[i], bf[j], acc[i][j], 0, 0, 0);
    }
    __syncthreads();
  }

  // ---- epilogue: stash q/k halves in LDS (f16), layout [row 0..127][h 0..63]
  {
    f16* dst = wc ? lds_b : lds_a;
    const int rbase = wr * 64 + (lane >> 4) * 4;
    const int hcol = lane & 15;
    #pragma unroll
    for (int i = 0; i < 4; ++i)
      #pragma unroll
      for (int j = 0; j < 4; ++j)
        #pragma unroll
        for (int r = 0; r < 4; ++r)
          dst[(size_t)(rbase + i * 16 + r) * 64 + j * 16 + hcol] = (f16)acc[i][j][r];
  }
  __syncthreads();

  // ---- 42 batches x 9 pairs, 64-length dots, write S_part[b][ht][9]
  for (int p = tid; p < RT_BATCH * 9; p += 256) {
    int bl = p / 9;
    int ij = p - bl * 9;
    int i = ij / 3, j = ij - i * 3;
    const f16* qp = &lds_a[(size_t)(bl * 3 + i) * 64];
    const f16* kp = &lds_b[(size_t)(bl * 3 + j) * 64];
    float s = 0.f;
    #pragma unroll
    for (int hc = 0; hc < 8; ++hc) {
      f16x8 qa = *(const f16x8*)(qp + hc * 8);
      f16x8 ka = *(const f16x8*)(kp + hc * 8);
      #pragma unroll
      for (int t = 0; t < 8; ++t) s += (float)qa[t] * (float)ka[t];
    }
    int b = rt * RT_BATCH + bl;
    if (b < B_) S_part[(size_t)b * (NHT * 9) + ht * 9 + ij] = s;
  }
}

// ---- kernel 5: reduce h-chunks, softmax, apply vf  (thread/batch) -------
__global__ void k_final(const float* __restrict__ S_part, const float* __restrict__ vf,
                        float* __restrict__ out) {
  int b = blockIdx.x * 256 + threadIdx.x;
  const float* sp = S_part + (size_t)b * (NHT * 9);
  float s[9] = {0,0,0,0,0,0,0,0,0};
  #pragma unroll
  for (int ht = 0; ht < NHT; ++ht)
    #pragma unroll
    for (int ij = 0; ij < 9; ++ij) s[ij] += sp[ht * 9 + ij];
  float attn[3] = {0.f, 0.f, 0.f};
  #pragma unroll
  for (int i = 0; i < 3; ++i) {
    float m = fmaxf(s[i*3+0], fmaxf(s[i*3+1], s[i*3+2]));
    float e0 = __expf(s[i*3+0] - m), e1 = __expf(s[i*3+1] - m), e2 = __expf(s[i*3+2] - m);
    float inv = 1.f / (e0 + e1 + e2);
    attn[0] += e0 * inv; attn[1] += e1 * inv; attn[2] += e2 * inv;
  }
  float o = attn[0] * vf[b * 3 + 0] + attn[1] * vf[b * 3 + 1] + attn[2] * vf[b * 3 + 2];
  out[b] = o * (1.f / 3.f);
}

extern "C" void kernel_launch(void* const* d_in, const int* in_sizes, int n_in,
                              void* d_out, int out_size, void* d_ws, size_t ws_size,
                              hipStream_t stream) {
  const float* x   = (const float*)d_in[0];
  const float* Wq  = (const float*)d_in[1];
  const float* Wk  = (const float*)d_in[2];
  const float* Wv  = (const float*)d_in[3];
  const float* Wfc = (const float*)d_in[4];
  float* out = (float*)d_out;

  char* ws = (char*)d_ws;
  f16*   Xh     = (f16*)(ws);                        // 201326592 B
  f16*   Wh     = (f16*)(ws + 201326592ull);         // 8388608 B
  float* wvf    = (float*)(ws + 209715200ull);       // 8192 B
  float* vf     = (float*)(ws + 209723392ull);       // 196608 B
  float* S_part = (float*)(ws + 209920000ull);       // 16384*144*4 = 9437184 B

  k_wvf  <<<64,              256, 0, stream>>>(Wv, Wfc, wvf);
  k_castw<<<2048,            256, 0, stream>>>(Wq, Wk, Wh);
  k_prep <<<ROWS / 4,        256, 0, stream>>>(x, wvf, Xh, vf);
  k_gemm <<<dim3(NHT, NRT),  256, 0, stream>>>(Xh, Wh, S_part);
  k_final<<<B_ / 256,        256, 0, stream>>>(S_part, vf, out);
}